// Round 2
// baseline (3383.202 us; speedup 1.0000x reference)
//
#include <hip/hip_runtime.h>
#include <cstdint>

typedef _Float16 f16;
typedef __attribute__((ext_vector_type(2))) _Float16 f16x2;
typedef __attribute__((ext_vector_type(8))) _Float16 f16x8;
typedef __attribute__((ext_vector_type(4))) float f32x4;
typedef __attribute__((ext_vector_type(2))) float f32x2;
typedef __attribute__((ext_vector_type(8))) unsigned short us8;   // 16 B — staging vector

#define NB   32
#define TIN  1600
#define CIN  80
#define TOUT 800
#define DH   512
#define NV   1000
#define NU   200
#define TXP  1604   // xpad time rows (1 left pad + 1600 + 3 tail)
#define THP  804    // conv buffer time rows (2 pad each side)
#define EPSB 1e-3f

// ---------------------------------------------------------------- init
__global__ void init_zero(float* gsum, float* gsumsq, float* hstate,
                          unsigned long long* cnt, f16* xpad, f16* hbufA, f16* hbufB)
{
    int tid = blockIdx.x * 256 + threadIdx.x;
    int stride = gridDim.x * 256;
    if (blockIdx.x == 0) {
        if (threadIdx.x < 80) { gsum[threadIdx.x] = 0.f; gsumsq[threadIdx.x] = 0.f; }
        if (threadIdx.x == 255) *cnt = 0ull;
    }
    for (int i = tid; i < NB * DH; i += stride) hstate[i] = 0.f;
    // xpad zero rows: t'=0, 1601..1603 per b
    for (int i = tid; i < NB * 4 * CIN; i += stride) {
        int b = i / (4 * CIN), rr = (i / CIN) % 4, c = i % CIN;
        int row = (rr == 0) ? 0 : (1600 + rr);
        xpad[((long)b * TXP + row) * CIN + c] = (f16)0.f;
    }
    // hbuf zero rows: t'=0,1,802,803 per b, both buffers
    for (int i = tid; i < 2 * NB * 4 * DH; i += stride) {
        int q = i; int buf = q / (NB * 4 * DH); q %= NB * 4 * DH;
        int b = q / (4 * DH); int rr = (q / DH) % 4; int dd = q % DH;
        int row = (rr < 2) ? rr : (800 + rr);
        f16* hb = buf ? hbufB : hbufA;
        hb[((long)b * THP + row) * DH + dd] = (f16)0.f;
    }
}

// ---------------------------------------------------------------- transpose f32 -> f16 (out[c][r] = in[r][c], OOB -> 0)
__global__ void transpose_f32_f16(const float* __restrict__ in, int R, int C,
                                  f16* __restrict__ out, int outRows, int outCols)
{
    __shared__ float t[32][33];
    int c0 = blockIdx.x * 32, r0 = blockIdx.y * 32;
    int x = threadIdx.x & 31, y = threadIdx.x >> 5;
    for (int i = y; i < 32; i += 8) {
        int r = r0 + i, c = c0 + x;
        t[i][x] = (r < R && c < C) ? in[(long)r * C + c] : 0.0f;
    }
    __syncthreads();
    for (int i = y; i < 32; i += 8) {
        int orow = c0 + i, ocol = r0 + x;
        if (orow < outRows && ocol < outCols)
            out[(long)orow * outCols + ocol] = (f16)t[x][i];
    }
}

// ---------------------------------------------------------------- batchnorm
__global__ void bn_stats(const float* __restrict__ x, float* gsum, float* gsumsq)
{
    __shared__ float ls[240], ls2[240];
    const float* base = x + (long)blockIdx.x * 200 * CIN;
    int tid = threadIdx.x;
    if (tid < 240) {
        int c = tid % 80, rg = tid / 80;
        float s = 0.f, s2 = 0.f;
        for (int r = rg; r < 200; r += 3) {
            float v = base[r * CIN + c];
            s += v; s2 += v * v;
        }
        ls[tid] = s; ls2[tid] = s2;
    }
    __syncthreads();
    if (tid < 80) {
        atomicAdd(&gsum[tid],   ls[tid] + ls[tid + 80] + ls[tid + 160]);
        atomicAdd(&gsumsq[tid], ls2[tid] + ls2[tid + 80] + ls2[tid + 160]);
    }
}

__global__ void bn_apply(const float* __restrict__ x, const float* __restrict__ gsum,
                         const float* __restrict__ gsumsq, const float* __restrict__ gamma,
                         const float* __restrict__ beta, f16* __restrict__ xpad)
{
    long idx = (long)blockIdx.x * 256 + threadIdx.x;
    if (idx >= (long)NB * TIN * CIN) return;
    int c = (int)(idx % CIN);
    long bt = idx / CIN;
    int t = (int)(bt % TIN); int b = (int)(bt / TIN);
    float mean = gsum[c] * (1.f / 51200.f);
    float var  = gsumsq[c] * (1.f / 51200.f) - mean * mean;
    float sc = gamma[c] * rsqrtf(var + EPSB);
    float sh = beta[c] - mean * sc;
    xpad[((long)b * TXP + t + 1) * CIN + c] = (f16)(x[idx] * sc + sh);
}

// ---------------------------------------------------------------- generic fp16 MFMA GEMM (64x128 tile, K in chunks of 64)
// MODE 0: conv0 (relu+bias -> f16 padded buf)   MODE 1: tcr (relu+bias+residual)
// MODE 2: attention scores (f32)                MODE 3: fc (bias -> f32 logits in d_out)
template<int MODE>
__launch_bounds__(256)
__global__ void gemm16(const f16* __restrict__ Ab, long strideA, long slabA,
                       const f16* __restrict__ Bb, long strideB, long slabB,
                       int M, int N, int Kchunks,
                       const float* __restrict__ bias,
                       const f16* __restrict__ resid, long slabR,
                       f16* __restrict__ outH, long slabO,
                       float* __restrict__ outF)
{
    __shared__ f16 As[64][72];
    __shared__ f16 Bs[128][72];
    const int b = blockIdx.z;
    const f16* Abase = Ab + (long)b * slabA;
    const f16* Bbase = Bb + (long)b * slabB;
    const int m0 = blockIdx.x * 64, n0 = blockIdx.y * 128;
    const int tid = threadIdx.x;
    const int lane = tid & 63, wv = tid >> 6;
    const int lm = lane & 15, lk = lane >> 4;

    f32x4 vzero = {0.f, 0.f, 0.f, 0.f};
    f32x4 acc[4][2];
#pragma unroll
    for (int i = 0; i < 4; i++) { acc[i][0] = vzero; acc[i][1] = vzero; }

    const int srow = tid >> 3, scol = (tid & 7) * 8;

    for (int kc = 0; kc < Kchunks; kc++) {
        int kb = kc * 64;
#pragma unroll
        for (int p = 0; p < 2; p++) {
            int r = srow + p * 32;
            int m = m0 + r; if (m > M - 1) m = M - 1;
            *(us8*)&As[r][scol] = *(const us8*)(Abase + (long)m * strideA + kb + scol);
        }
#pragma unroll
        for (int p = 0; p < 4; p++) {
            int r = srow + p * 32;
            int n = n0 + r; if (n > N - 1) n = N - 1;
            *(us8*)&Bs[r][scol] = *(const us8*)(Bbase + (long)n * strideB + kb + scol);
        }
        __syncthreads();
#pragma unroll
        for (int ks = 0; ks < 2; ks++) {
            f16x8 af[4], bf[2];
#pragma unroll
            for (int mt = 0; mt < 4; mt++)
                af[mt] = *(const f16x8*)&As[mt * 16 + lm][ks * 32 + lk * 8];
#pragma unroll
            for (int nt = 0; nt < 2; nt++)
                bf[nt] = *(const f16x8*)&Bs[wv * 32 + nt * 16 + lm][ks * 32 + lk * 8];
#pragma unroll
            for (int mt = 0; mt < 4; mt++)
#pragma unroll
                for (int nt = 0; nt < 2; nt++)
                    acc[mt][nt] = __builtin_amdgcn_mfma_f32_16x16x32_f16(af[mt], bf[nt], acc[mt][nt], 0, 0, 0);
        }
        __syncthreads();
    }
#pragma unroll
    for (int mt = 0; mt < 4; mt++) {
#pragma unroll
        for (int nt = 0; nt < 2; nt++) {
            int n = n0 + wv * 32 + nt * 16 + lm;
#pragma unroll
            for (int reg = 0; reg < 4; reg++) {
                int m = m0 + mt * 16 + lk * 4 + reg;
                if (m >= M || n >= N) continue;
                float v = acc[mt][nt][reg];
                if (MODE == 0) {
                    v += bias[n]; v = v > 0.f ? v : 0.f;
                    outH[(long)b * slabO + (long)(2 + m) * DH + n] = (f16)v;
                } else if (MODE == 1) {
                    v += bias[n]; v = v > 0.f ? v : 0.f;
                    v += (float)resid[(long)b * slabR + (long)(2 + m) * DH + n];
                    outH[(long)b * slabO + (long)(2 + m) * DH + n] = (f16)v;
                } else if (MODE == 2) {
                    outF[((long)b * NU + m) * 800 + n] = v;
                } else {
                    v += bias[n];
                    int u = m >> 5, bb = m & 31;
                    outF[((long)bb * NU + u) * 1000 + n] = v;
                }
            }
        }
    }
}

// ---------------------------------------------------------------- GRU: persistent 8-WG kernel, weights resident in VGPRs,
// device-scope barrier per step (all 8 WGs trivially co-resident on 256 CUs)
__launch_bounds__(256, 1)
__global__ void gru_seq(const f16* __restrict__ wrecT, const float* __restrict__ gk,
                        const float* __restrict__ gbias, const int* __restrict__ ytrue,
                        float* __restrict__ hstate, f16* __restrict__ Hc,
                        unsigned long long* __restrict__ cnt)
{
    __shared__ f16 hl[32][520];
    __shared__ int yl[32];
    const int tid = threadIdx.x;
    const int lane = tid & 63, wv = tid >> 6;
    const int gw = blockIdx.x * 4 + wv;          // gate-triple index 0..31
    const int lm = lane & 15, lk = lane >> 4;
    const int j = gw * 16 + lm;                  // hidden column 0..511

    // resident B-fragments for z/r/c gate columns: wf[g][ks]
    f16x8 wf[3][16];
#pragma unroll
    for (int g = 0; g < 3; g++)
#pragma unroll
        for (int ks = 0; ks < 16; ks++)
            wf[g][ks] = *(const f16x8*)&wrecT[(long)(g * 512 + j) * 512 + ks * 32 + lk * 8];

    const float biz = gbias[j],        bir = gbias[512 + j],        bic = gbias[1024 + j];
    const float brz = gbias[1536 + j], brr = gbias[1536 + 512 + j], brc = gbias[1536 + 1024 + j];
    f32x4 vzero = {0.f, 0.f, 0.f, 0.f};

    for (int u = 0; u < NU; u++) {
        // stage h (f32 global -> f16 LDS)
#pragma unroll
        for (int i = 0; i < 16; i++) {
            int off = i * 1024 + tid * 4;
            float4 hv = *(const float4*)&hstate[off];
            int row = off >> 9, col = off & 511;
            f16* p = &hl[row][col];
            p[0] = (f16)hv.x; p[1] = (f16)hv.y; p[2] = (f16)hv.z; p[3] = (f16)hv.w;
        }
        if (tid < 32) yl[tid] = ytrue[tid * 201 + u];
        __syncthreads();

        f32x4 acc[3][2];
#pragma unroll
        for (int g = 0; g < 3; g++) { acc[g][0] = vzero; acc[g][1] = vzero; }
#pragma unroll
        for (int ks = 0; ks < 16; ks++) {
            f16x8 a0 = *(const f16x8*)&hl[lm][ks * 32 + lk * 8];
            f16x8 a1 = *(const f16x8*)&hl[16 + lm][ks * 32 + lk * 8];
#pragma unroll
            for (int g = 0; g < 3; g++) {
                acc[g][0] = __builtin_amdgcn_mfma_f32_16x16x32_f16(a0, wf[g][ks], acc[g][0], 0, 0, 0);
                acc[g][1] = __builtin_amdgcn_mfma_f32_16x16x32_f16(a1, wf[g][ks], acc[g][1], 0, 0, 0);
            }
        }
        // gates + state update (fp32)
#pragma unroll
        for (int mt = 0; mt < 2; mt++) {
#pragma unroll
            for (int reg = 0; reg < 4; reg++) {
                int b = mt * 16 + lk * 4 + reg;
                const float* gkr = gk + (long)yl[b] * 1536;
                float xz = gkr[j] + biz, xr = gkr[512 + j] + bir, xh = gkr[1024 + j] + bic;
                float hz = acc[0][mt][reg] + brz;
                float hr = acc[1][mt][reg] + brr;
                float hh = acc[2][mt][reg] + brc;
                float z = 1.f / (1.f + __expf(-(xz + hz)));
                float r = 1.f / (1.f + __expf(-(xr + hr)));
                float cd = tanhf(xh + r * hh);
                float hold = hstate[b * DH + j];
                float hnew = z * hold + (1.f - z) * cd;
                hstate[b * DH + j] = hnew;
                Hc[((long)u * 32 + b) * 1024 + j] = (f16)hnew;
            }
        }
        __threadfence();
        __syncthreads();
        if (u < NU - 1) {
            if (tid == 0) {
                __hip_atomic_fetch_add(cnt, 1ull, __ATOMIC_RELEASE, __HIP_MEMORY_SCOPE_AGENT);
                unsigned long long target = 8ull * (unsigned long long)(u + 1);
                while (__hip_atomic_load(cnt, __ATOMIC_ACQUIRE, __HIP_MEMORY_SCOPE_AGENT) < target)
                    __builtin_amdgcn_s_sleep(8);
            }
            __syncthreads();
        }
    }
}

// ---------------------------------------------------------------- row softmax in place (len <= 1024)
__global__ void row_softmax(float* __restrict__ base, int len)
{
    float* s = base + (long)blockIdx.x * len;
    int tid = threadIdx.x;
    float v[4]; float mx = -1e30f;
#pragma unroll
    for (int i = 0; i < 4; i++) {
        int idx = tid + i * 256;
        v[i] = (idx < len) ? s[idx] : -1e30f;
        mx = fmaxf(mx, v[i]);
    }
#pragma unroll
    for (int off = 32; off; off >>= 1) mx = fmaxf(mx, __shfl_xor(mx, off));
    __shared__ float red[4], red2[4];
    if ((tid & 63) == 0) red[tid >> 6] = mx;
    __syncthreads();
    mx = fmaxf(fmaxf(red[0], red[1]), fmaxf(red[2], red[3]));
    float sum = 0.f;
#pragma unroll
    for (int i = 0; i < 4; i++) { v[i] = __expf(v[i] - mx); sum += v[i]; }
#pragma unroll
    for (int off = 32; off; off >>= 1) sum += __shfl_xor(sum, off);
    if ((tid & 63) == 0) red2[tid >> 6] = sum;
    __syncthreads();
    sum = red2[0] + red2[1] + red2[2] + red2[3];
    float inv = 1.f / sum;
#pragma unroll
    for (int i = 0; i < 4; i++) {
        int idx = tid + i * 256;
        if (idx < len) s[idx] = v[i] * inv;
    }
}

// ---------------------------------------------------------------- ctx: ctx[b][u][:] = alpha[b][u][:] @ enc[b], u-blocked by 16
__global__ void ctx_kernel(const float* __restrict__ alpha, const f16* __restrict__ enc,
                           f16* __restrict__ Hc)
{
    __shared__ float al[800][18];
    int b = blockIdx.x, ut = blockIdx.y;
    int u0 = ut * 16;
    int tid = threadIdx.x;
    for (int ul = 0; ul < 16; ul++) {
        int u = u0 + ul;
        if (u < NU) {
            const float* arow = alpha + ((long)b * NU + u) * 800;
            for (int t = tid; t < 800; t += 256) al[t][ul] = arow[t];
        } else {
            for (int t = tid; t < 800; t += 256) al[t][ul] = 0.f;
        }
    }
    __syncthreads();
    int d0 = tid * 2;
    float a0[16], a1[16];
#pragma unroll
    for (int i = 0; i < 16; i++) { a0[i] = 0.f; a1[i] = 0.f; }
    const f16* encb = enc + ((long)b * THP + 2) * DH + d0;
    for (int t = 0; t < 800; t++) {
        f16x2 e = *(const f16x2*)&encb[(long)t * DH];
        float f0 = (float)e.x, f1 = (float)e.y;
#pragma unroll
        for (int g = 0; g < 8; g++) {
            f32x2 ap = *(const f32x2*)&al[t][2 * g];
            a0[2 * g]     += ap.x * f0; a0[2 * g + 1] += ap.y * f0;
            a1[2 * g]     += ap.x * f1; a1[2 * g + 1] += ap.y * f1;
        }
    }
#pragma unroll
    for (int ul = 0; ul < 16; ul++) {
        int u = u0 + ul;
        if (u < NU) {
            Hc[((long)u * 32 + b) * 1024 + 512 + d0]     = (f16)a0[ul];
            Hc[((long)u * 32 + b) * 1024 + 512 + d0 + 1] = (f16)a1[ul];
        }
    }
}

// ---------------------------------------------------------------- launcher
extern "C" void kernel_launch(void* const* d_in, const int* in_sizes, int n_in,
                              void* d_out, int out_size, void* d_ws, size_t ws_size,
                              hipStream_t stream)
{
    const float* x     = (const float*)d_in[0];
    const int*   ytrue = (const int*)d_in[1];
    const float* gamma = (const float*)d_in[2];
    const float* beta  = (const float*)d_in[3];
    const float* w0    = (const float*)d_in[4];
    const float* b0    = (const float*)d_in[5];
    const float* tcrw  = (const float*)d_in[6];
    const float* tcrb  = (const float*)d_in[7];
    const float* gk    = (const float*)d_in[8];
    const float* grk   = (const float*)d_in[9];
    const float* gbias = (const float*)d_in[10];
    const float* fcw   = (const float*)d_in[11];
    const float* fcb   = (const float*)d_in[12];
    float* out = (float*)d_out;
    (void)in_sizes; (void)n_in; (void)out_size; (void)ws_size;

    char* ws = (char*)d_ws;
    size_t o = 0;
    auto alloc = [&](size_t bytes) { size_t r = o; o += (bytes + 255) & ~(size_t)255; return r; };
    f16*   xpad   = (f16*)(ws + alloc((size_t)NB * TXP * CIN * 2));
    f16*   hbufA  = (f16*)(ws + alloc((size_t)NB * THP * DH * 2));
    f16*   hbufB  = (f16*)(ws + alloc((size_t)NB * THP * DH * 2));
    f16*   Hc     = (f16*)(ws + alloc((size_t)NU * NB * 1024 * 2));
    float* hstate = (float*)(ws + alloc((size_t)NB * DH * 4));
    float* scores = (float*)(ws + alloc((size_t)NB * NU * 800 * 4));
    f16*   w0T    = (f16*)(ws + alloc((size_t)512 * 448 * 2));
    f16*   tcrT   = (f16*)(ws + alloc((size_t)4 * 512 * 2560 * 2));
    f16*   wrecT  = (f16*)(ws + alloc((size_t)1536 * 512 * 2));
    f16*   fcT    = (f16*)(ws + alloc((size_t)1024 * 1024 * 2));
    float* gsum   = (float*)(ws + alloc(80 * 4));
    float* gsumsq = (float*)(ws + alloc(80 * 4));
    unsigned long long* cnt = (unsigned long long*)(ws + alloc(64));

    init_zero<<<64, 256, 0, stream>>>(gsum, gsumsq, hstate, cnt, xpad, hbufA, hbufB);
    transpose_f32_f16<<<dim3(16, 14), 256, 0, stream>>>(w0, 400, 512, w0T, 512, 448);
    for (int i = 0; i < 4; i++)
        transpose_f32_f16<<<dim3(16, 80), 256, 0, stream>>>(tcrw + (size_t)i * 2560 * 512, 2560, 512,
                                                            tcrT + (size_t)i * 512 * 2560, 512, 2560);
    transpose_f32_f16<<<dim3(48, 16), 256, 0, stream>>>(grk, 512, 1536, wrecT, 1536, 512);
    transpose_f32_f16<<<dim3(32, 32), 256, 0, stream>>>(fcw, 1024, 1000, fcT, 1024, 1024);

    bn_stats<<<256, 256, 0, stream>>>(x, gsum, gsumsq);
    bn_apply<<<16000, 256, 0, stream>>>(x, gsum, gsumsq, gamma, beta, xpad);

    // conv0: A[t][kk] = xpad_flat[160 t + kk], K padded 400->448 (zero weights)
    gemm16<0><<<dim3(13, 4, 32), 256, 0, stream>>>(xpad, 160, (long)TXP * CIN, w0T, 448, 0,
        800, 512, 7, b0, nullptr, 0, hbufA, (long)THP * DH, nullptr);

    const f16* tin = hbufA; f16* tout = hbufB;
    for (int i = 0; i < 4; i++) {
        gemm16<1><<<dim3(13, 4, 32), 256, 0, stream>>>(tin, 512, (long)THP * DH,
            tcrT + (size_t)i * 512 * 2560, 2560, 0,
            800, 512, 40, tcrb + i * 512, tin, (long)THP * DH, tout, (long)THP * DH, nullptr);
        const f16* t2 = tout; tout = (f16*)tin; tin = t2;
    }
    const f16* enc = tin;   // = hbufA after 4 swaps

    gru_seq<<<8, 256, 0, stream>>>(wrecT, gk, gbias, ytrue, hstate, Hc, cnt);

    // scores[b][u][t] = Hc[u][b][:512] . enc[b][t][:]
    gemm16<2><<<dim3(4, 7, 32), 256, 0, stream>>>(Hc, 32 * 1024, 1024, enc + 2 * DH, 512, (long)THP * DH,
        200, 800, 8, nullptr, nullptr, 0, nullptr, 0, scores);
    row_softmax<<<6400, 256, 0, stream>>>(scores, 800);
    ctx_kernel<<<dim3(32, 13), 256, 0, stream>>>(scores, enc, Hc);

    // logits[b][u][v] = Hc_row(u*32+b)[0:1024] @ fcT + fc_b  -> d_out
    gemm16<3><<<dim3(100, 8, 1), 256, 0, stream>>>(Hc, 1024, 0, fcT, 1024, 0,
        6400, 1000, 16, fcb, nullptr, 0, nullptr, 0, out);
    row_softmax<<<6400, 256, 0, stream>>>(out, 1000);
}

// Round 3
// 2362.786 us; speedup vs baseline: 1.4319x; 1.4319x over previous
//
#include <hip/hip_runtime.h>
#include <cstdint>

typedef _Float16 f16;
typedef __attribute__((ext_vector_type(2))) _Float16 f16x2;
typedef __attribute__((ext_vector_type(8))) _Float16 f16x8;
typedef __attribute__((ext_vector_type(4))) float f32x4;
typedef __attribute__((ext_vector_type(2))) float f32x2;
typedef __attribute__((ext_vector_type(8))) unsigned short us8;   // 16 B — staging vector

#define NB   32
#define TIN  1600
#define CIN  80
#define TOUT 800
#define DH   512
#define NV   1000
#define NU   200
#define TXP  1604   // xpad time rows (1 left pad + 1600 + 3 tail)
#define THP  804    // conv buffer time rows (2 pad each side)
#define EPSB 1e-3f

// ---------------------------------------------------------------- init
__global__ void init_zero(float* gsum, float* gsumsq,
                          unsigned long long* cnt, f16* xpad, f16* hbufA, f16* hbufB)
{
    int tid = blockIdx.x * 256 + threadIdx.x;
    int stride = gridDim.x * 256;
    if (blockIdx.x == 0) {
        if (threadIdx.x < 80) { gsum[threadIdx.x] = 0.f; gsumsq[threadIdx.x] = 0.f; }
        if (threadIdx.x == 255) *cnt = 0ull;
    }
    // xpad zero rows: t'=0, 1601..1603 per b
    for (int i = tid; i < NB * 4 * CIN; i += stride) {
        int b = i / (4 * CIN), rr = (i / CIN) % 4, c = i % CIN;
        int row = (rr == 0) ? 0 : (1600 + rr);
        xpad[((long)b * TXP + row) * CIN + c] = (f16)0.f;
    }
    // hbuf zero rows: t'=0,1,802,803 per b, both buffers
    for (int i = tid; i < 2 * NB * 4 * DH; i += stride) {
        int q = i; int buf = q / (NB * 4 * DH); q %= NB * 4 * DH;
        int b = q / (4 * DH); int rr = (q / DH) % 4; int dd = q % DH;
        int row = (rr < 2) ? rr : (800 + rr);
        f16* hb = buf ? hbufB : hbufA;
        hb[((long)b * THP + row) * DH + dd] = (f16)0.f;
    }
}

// ---------------------------------------------------------------- transpose f32 -> f16 (out[c][r] = in[r][c], OOB -> 0)
__global__ void transpose_f32_f16(const float* __restrict__ in, int R, int C,
                                  f16* __restrict__ out, int outRows, int outCols)
{
    __shared__ float t[32][33];
    int c0 = blockIdx.x * 32, r0 = blockIdx.y * 32;
    int x = threadIdx.x & 31, y = threadIdx.x >> 5;
    for (int i = y; i < 32; i += 8) {
        int r = r0 + i, c = c0 + x;
        t[i][x] = (r < R && c < C) ? in[(long)r * C + c] : 0.0f;
    }
    __syncthreads();
    for (int i = y; i < 32; i += 8) {
        int orow = c0 + i, ocol = r0 + x;
        if (orow < outRows && ocol < outCols)
            out[(long)orow * outCols + ocol] = (f16)t[x][i];
    }
}

// ---------------------------------------------------------------- batchnorm
__global__ void bn_stats(const float* __restrict__ x, float* gsum, float* gsumsq)
{
    __shared__ float ls[240], ls2[240];
    const float* base = x + (long)blockIdx.x * 200 * CIN;
    int tid = threadIdx.x;
    if (tid < 240) {
        int c = tid % 80, rg = tid / 80;
        float s = 0.f, s2 = 0.f;
        for (int r = rg; r < 200; r += 3) {
            float v = base[r * CIN + c];
            s += v; s2 += v * v;
        }
        ls[tid] = s; ls2[tid] = s2;
    }
    __syncthreads();
    if (tid < 80) {
        atomicAdd(&gsum[tid],   ls[tid] + ls[tid + 80] + ls[tid + 160]);
        atomicAdd(&gsumsq[tid], ls2[tid] + ls2[tid + 80] + ls2[tid + 160]);
    }
}

__global__ void bn_apply(const float* __restrict__ x, const float* __restrict__ gsum,
                         const float* __restrict__ gsumsq, const float* __restrict__ gamma,
                         const float* __restrict__ beta, f16* __restrict__ xpad)
{
    long idx = (long)blockIdx.x * 256 + threadIdx.x;
    if (idx >= (long)NB * TIN * CIN) return;
    int c = (int)(idx % CIN);
    long bt = idx / CIN;
    int t = (int)(bt % TIN); int b = (int)(bt / TIN);
    float mean = gsum[c] * (1.f / 51200.f);
    float var  = gsumsq[c] * (1.f / 51200.f) - mean * mean;
    float sc = gamma[c] * rsqrtf(var + EPSB);
    float sh = beta[c] - mean * sc;
    xpad[((long)b * TXP + t + 1) * CIN + c] = (f16)(x[idx] * sc + sh);
}

// ---------------------------------------------------------------- generic fp16 MFMA GEMM (64x128 tile, K in chunks of 64)
// MODE 0: conv0 (relu+bias -> f16 padded buf)   MODE 1: tcr (relu+bias+residual)
// MODE 2: attention scores (f32)                MODE 3: fc (bias -> f32 logits in d_out)
template<int MODE>
__launch_bounds__(256)
__global__ void gemm16(const f16* __restrict__ Ab, long strideA, long slabA,
                       const f16* __restrict__ Bb, long strideB, long slabB,
                       int M, int N, int Kchunks,
                       const float* __restrict__ bias,
                       const f16* __restrict__ resid, long slabR,
                       f16* __restrict__ outH, long slabO,
                       float* __restrict__ outF)
{
    __shared__ f16 As[64][72];
    __shared__ f16 Bs[128][72];
    const int b = blockIdx.z;
    const f16* Abase = Ab + (long)b * slabA;
    const f16* Bbase = Bb + (long)b * slabB;
    const int m0 = blockIdx.x * 64, n0 = blockIdx.y * 128;
    const int tid = threadIdx.x;
    const int lane = tid & 63, wv = tid >> 6;
    const int lm = lane & 15, lk = lane >> 4;

    f32x4 vzero = {0.f, 0.f, 0.f, 0.f};
    f32x4 acc[4][2];
#pragma unroll
    for (int i = 0; i < 4; i++) { acc[i][0] = vzero; acc[i][1] = vzero; }

    const int srow = tid >> 3, scol = (tid & 7) * 8;

    for (int kc = 0; kc < Kchunks; kc++) {
        int kb = kc * 64;
#pragma unroll
        for (int p = 0; p < 2; p++) {
            int r = srow + p * 32;
            int m = m0 + r; if (m > M - 1) m = M - 1;
            *(us8*)&As[r][scol] = *(const us8*)(Abase + (long)m * strideA + kb + scol);
        }
#pragma unroll
        for (int p = 0; p < 4; p++) {
            int r = srow + p * 32;
            int n = n0 + r; if (n > N - 1) n = N - 1;
            *(us8*)&Bs[r][scol] = *(const us8*)(Bbase + (long)n * strideB + kb + scol);
        }
        __syncthreads();
#pragma unroll
        for (int ks = 0; ks < 2; ks++) {
            f16x8 af[4], bf[2];
#pragma unroll
            for (int mt = 0; mt < 4; mt++)
                af[mt] = *(const f16x8*)&As[mt * 16 + lm][ks * 32 + lk * 8];
#pragma unroll
            for (int nt = 0; nt < 2; nt++)
                bf[nt] = *(const f16x8*)&Bs[wv * 32 + nt * 16 + lm][ks * 32 + lk * 8];
#pragma unroll
            for (int mt = 0; mt < 4; mt++)
#pragma unroll
                for (int nt = 0; nt < 2; nt++)
                    acc[mt][nt] = __builtin_amdgcn_mfma_f32_16x16x32_f16(af[mt], bf[nt], acc[mt][nt], 0, 0, 0);
        }
        __syncthreads();
    }
#pragma unroll
    for (int mt = 0; mt < 4; mt++) {
#pragma unroll
        for (int nt = 0; nt < 2; nt++) {
            int n = n0 + wv * 32 + nt * 16 + lm;
#pragma unroll
            for (int reg = 0; reg < 4; reg++) {
                int m = m0 + mt * 16 + lk * 4 + reg;
                if (m >= M || n >= N) continue;
                float v = acc[mt][nt][reg];
                if (MODE == 0) {
                    v += bias[n]; v = v > 0.f ? v : 0.f;
                    outH[(long)b * slabO + (long)(2 + m) * DH + n] = (f16)v;
                } else if (MODE == 1) {
                    v += bias[n]; v = v > 0.f ? v : 0.f;
                    v += (float)resid[(long)b * slabR + (long)(2 + m) * DH + n];
                    outH[(long)b * slabO + (long)(2 + m) * DH + n] = (f16)v;
                } else if (MODE == 2) {
                    outF[((long)b * NU + m) * 800 + n] = v;
                } else {
                    v += bias[n];
                    int u = m >> 5, bb = m & 31;
                    outF[((long)bb * NU + u) * 1000 + n] = v;
                }
            }
        }
    }
}

// ---------------------------------------------------------------- GRU: persistent 8-WG kernel, weights resident in VGPRs.
// h columns owned per-lane in f32 regs; cross-WG exchange is f16 via Hc only;
// A-fragments loaded directly global->VGPR; gk gather prefetched one step ahead;
// barrier: relaxed spin + single acquire (no per-poll L2 invalidate).
__launch_bounds__(256, 1)
__global__ void gru_seq(const f16* __restrict__ wrecT, const float* __restrict__ gk,
                        const float* __restrict__ gbias, const int* __restrict__ ytrue,
                        f16* __restrict__ Hc, unsigned long long* __restrict__ cnt)
{
    __shared__ int yl[NU * 32];                  // yl[u*32+b]
    const int tid = threadIdx.x;
    const int lane = tid & 63, wv = tid >> 6;
    const int gw = blockIdx.x * 4 + wv;          // gate-triple index 0..31
    const int lm = lane & 15, lk = lane >> 4;
    const int j = gw * 16 + lm;                  // hidden column 0..511

    // stage all teacher-forcing labels once (u = 0..199 of the 201 columns)
    for (int i = tid; i < NU * 32; i += 256) {
        int b = i / NU, u = i - b * NU;
        yl[u * 32 + b] = ytrue[b * 201 + u];
    }

    // resident B-fragments for z/r/c gate columns: wf[g][ks]
    f16x8 wf[3][16];
#pragma unroll
    for (int g = 0; g < 3; g++)
#pragma unroll
        for (int ks = 0; ks < 16; ks++)
            wf[g][ks] = *(const f16x8*)&wrecT[(long)(g * 512 + j) * 512 + ks * 32 + lk * 8];

    const float biz = gbias[j],        bir = gbias[512 + j],        bic = gbias[1024 + j];
    const float brz = gbias[1536 + j], brr = gbias[1536 + 512 + j], brc = gbias[1536 + 1024 + j];
    f32x4 vzero = {0.f, 0.f, 0.f, 0.f};

    __syncthreads();   // yl visible

    // per-lane persistent h (own columns) + double-buffered gk gather
    float hold[8];
    float nxz[8], nxr[8], nxh[8], mxz[8], mxr[8], mxh[8];
#pragma unroll
    for (int s = 0; s < 8; s++) {
        hold[s] = 0.f;
        int b = ((s >> 2) << 4) + lk * 4 + (s & 3);
        const float* gkr = gk + (long)yl[b] * 1536;        // u = 0
        nxz[s] = gkr[j]; nxr[s] = gkr[512 + j]; nxh[s] = gkr[1024 + j];
    }

    for (int u = 0; u < NU; u++) {
        // prefetch gather for u+1 (overlaps barrier wait; gk is constant so the
        // acquire-invalidate below cannot produce stale data)
        int up = (u < NU - 1) ? u + 1 : u;
#pragma unroll
        for (int s = 0; s < 8; s++) {
            int b = ((s >> 2) << 4) + lk * 4 + (s & 3);
            const float* gkr = gk + (long)yl[up * 32 + b] * 1536;
            mxz[s] = gkr[j]; mxr[s] = gkr[512 + j]; mxh[s] = gkr[1024 + j];
        }

        f32x4 acc[3][2];
#pragma unroll
        for (int g = 0; g < 3; g++) { acc[g][0] = vzero; acc[g][1] = vzero; }

        if (u > 0) {
            if (tid == 0) {
                unsigned long long target = 8ull * (unsigned long long)u;
                while (__hip_atomic_load(cnt, __ATOMIC_RELAXED, __HIP_MEMORY_SCOPE_AGENT) < target)
                    __builtin_amdgcn_s_sleep(1);
                (void)__hip_atomic_load(cnt, __ATOMIC_ACQUIRE, __HIP_MEMORY_SCOPE_AGENT);
            }
            __syncthreads();
            // A-fragments directly from Hc[u-1]
            const f16* hrow = Hc + (long)(u - 1) * 32 * 1024 + lk * 8;
#pragma unroll
            for (int ks = 0; ks < 16; ks++) {
                f16x8 a0 = *(const f16x8*)(hrow + (long)lm * 1024 + ks * 32);
                f16x8 a1 = *(const f16x8*)(hrow + (long)(16 + lm) * 1024 + ks * 32);
#pragma unroll
                for (int g = 0; g < 3; g++) {
                    acc[g][0] = __builtin_amdgcn_mfma_f32_16x16x32_f16(a0, wf[g][ks], acc[g][0], 0, 0, 0);
                    acc[g][1] = __builtin_amdgcn_mfma_f32_16x16x32_f16(a1, wf[g][ks], acc[g][1], 0, 0, 0);
                }
            }
        }

        // gates + state update (fp32, h kept in regs)
#pragma unroll
        for (int mt = 0; mt < 2; mt++) {
#pragma unroll
            for (int reg = 0; reg < 4; reg++) {
                int s = mt * 4 + reg;
                int b = mt * 16 + lk * 4 + reg;
                float hz = acc[0][mt][reg] + brz;
                float hr = acc[1][mt][reg] + brr;
                float hh = acc[2][mt][reg] + brc;
                float z = 1.f / (1.f + __expf(-(nxz[s] + biz + hz)));
                float r = 1.f / (1.f + __expf(-(nxr[s] + bir + hr)));
                float cd = tanhf(nxh[s] + bic + r * hh);
                float hnew = z * hold[s] + (1.f - z) * cd;
                hold[s] = hnew;
                Hc[((long)u * 32 + b) * 1024 + j] = (f16)hnew;
            }
        }
#pragma unroll
        for (int s = 0; s < 8; s++) { nxz[s] = mxz[s]; nxr[s] = mxr[s]; nxh[s] = mxh[s]; }

        if (u < NU - 1) {
            __syncthreads();   // drains vmcnt(0): all lanes' Hc stores in L2
            if (tid == 0)
                __hip_atomic_fetch_add(cnt, 1ull, __ATOMIC_RELEASE, __HIP_MEMORY_SCOPE_AGENT);
        }
    }
}

// ---------------------------------------------------------------- row softmax in place (len <= 1024)
__global__ void row_softmax(float* __restrict__ base, int len)
{
    float* s = base + (long)blockIdx.x * len;
    int tid = threadIdx.x;
    float v[4]; float mx = -1e30f;
#pragma unroll
    for (int i = 0; i < 4; i++) {
        int idx = tid + i * 256;
        v[i] = (idx < len) ? s[idx] : -1e30f;
        mx = fmaxf(mx, v[i]);
    }
#pragma unroll
    for (int off = 32; off; off >>= 1) mx = fmaxf(mx, __shfl_xor(mx, off));
    __shared__ float red[4], red2[4];
    if ((tid & 63) == 0) red[tid >> 6] = mx;
    __syncthreads();
    mx = fmaxf(fmaxf(red[0], red[1]), fmaxf(red[2], red[3]));
    float sum = 0.f;
#pragma unroll
    for (int i = 0; i < 4; i++) { v[i] = __expf(v[i] - mx); sum += v[i]; }
#pragma unroll
    for (int off = 32; off; off >>= 1) sum += __shfl_xor(sum, off);
    if ((tid & 63) == 0) red2[tid >> 6] = sum;
    __syncthreads();
    sum = red2[0] + red2[1] + red2[2] + red2[3];
    float inv = 1.f / sum;
#pragma unroll
    for (int i = 0; i < 4; i++) {
        int idx = tid + i * 256;
        if (idx < len) s[idx] = v[i] * inv;
    }
}

// ---------------------------------------------------------------- ctx: ctx[b][u][:] = alpha[b][u][:] @ enc[b], u-blocked by 16
__global__ void ctx_kernel(const float* __restrict__ alpha, const f16* __restrict__ enc,
                           f16* __restrict__ Hc)
{
    __shared__ float al[800][18];
    int b = blockIdx.x, ut = blockIdx.y;
    int u0 = ut * 16;
    int tid = threadIdx.x;
    for (int ul = 0; ul < 16; ul++) {
        int u = u0 + ul;
        if (u < NU) {
            const float* arow = alpha + ((long)b * NU + u) * 800;
            for (int t = tid; t < 800; t += 256) al[t][ul] = arow[t];
        } else {
            for (int t = tid; t < 800; t += 256) al[t][ul] = 0.f;
        }
    }
    __syncthreads();
    int d0 = tid * 2;
    float a0[16], a1[16];
#pragma unroll
    for (int i = 0; i < 16; i++) { a0[i] = 0.f; a1[i] = 0.f; }
    const f16* encb = enc + ((long)b * THP + 2) * DH + d0;
    for (int t = 0; t < 800; t++) {
        f16x2 e = *(const f16x2*)&encb[(long)t * DH];
        float f0 = (float)e.x, f1 = (float)e.y;
#pragma unroll
        for (int g = 0; g < 8; g++) {
            f32x2 ap = *(const f32x2*)&al[t][2 * g];
            a0[2 * g]     += ap.x * f0; a0[2 * g + 1] += ap.y * f0;
            a1[2 * g]     += ap.x * f1; a1[2 * g + 1] += ap.y * f1;
        }
    }
#pragma unroll
    for (int ul = 0; ul < 16; ul++) {
        int u = u0 + ul;
        if (u < NU) {
            Hc[((long)u * 32 + b) * 1024 + 512 + d0]     = (f16)a0[ul];
            Hc[((long)u * 32 + b) * 1024 + 512 + d0 + 1] = (f16)a1[ul];
        }
    }
}

// ---------------------------------------------------------------- launcher
extern "C" void kernel_launch(void* const* d_in, const int* in_sizes, int n_in,
                              void* d_out, int out_size, void* d_ws, size_t ws_size,
                              hipStream_t stream)
{
    const float* x     = (const float*)d_in[0];
    const int*   ytrue = (const int*)d_in[1];
    const float* gamma = (const float*)d_in[2];
    const float* beta  = (const float*)d_in[3];
    const float* w0    = (const float*)d_in[4];
    const float* b0    = (const float*)d_in[5];
    const float* tcrw  = (const float*)d_in[6];
    const float* tcrb  = (const float*)d_in[7];
    const float* gk    = (const float*)d_in[8];
    const float* grk   = (const float*)d_in[9];
    const float* gbias = (const float*)d_in[10];
    const float* fcw   = (const float*)d_in[11];
    const float* fcb   = (const float*)d_in[12];
    float* out = (float*)d_out;
    (void)in_sizes; (void)n_in; (void)out_size; (void)ws_size;

    char* ws = (char*)d_ws;
    size_t o = 0;
    auto alloc = [&](size_t bytes) { size_t r = o; o += (bytes + 255) & ~(size_t)255; return r; };
    f16*   xpad   = (f16*)(ws + alloc((size_t)NB * TXP * CIN * 2));
    f16*   hbufA  = (f16*)(ws + alloc((size_t)NB * THP * DH * 2));
    f16*   hbufB  = (f16*)(ws + alloc((size_t)NB * THP * DH * 2));
    f16*   Hc     = (f16*)(ws + alloc((size_t)NU * NB * 1024 * 2));
    float* scores = (float*)(ws + alloc((size_t)NB * NU * 800 * 4));
    f16*   w0T    = (f16*)(ws + alloc((size_t)512 * 448 * 2));
    f16*   tcrT   = (f16*)(ws + alloc((size_t)4 * 512 * 2560 * 2));
    f16*   wrecT  = (f16*)(ws + alloc((size_t)1536 * 512 * 2));
    f16*   fcT    = (f16*)(ws + alloc((size_t)1024 * 1024 * 2));
    float* gsum   = (float*)(ws + alloc(80 * 4));
    float* gsumsq = (float*)(ws + alloc(80 * 4));
    unsigned long long* cnt = (unsigned long long*)(ws + alloc(64));

    init_zero<<<64, 256, 0, stream>>>(gsum, gsumsq, cnt, xpad, hbufA, hbufB);
    transpose_f32_f16<<<dim3(16, 14), 256, 0, stream>>>(w0, 400, 512, w0T, 512, 448);
    for (int i = 0; i < 4; i++)
        transpose_f32_f16<<<dim3(16, 80), 256, 0, stream>>>(tcrw + (size_t)i * 2560 * 512, 2560, 512,
                                                            tcrT + (size_t)i * 512 * 2560, 512, 2560);
    transpose_f32_f16<<<dim3(48, 16), 256, 0, stream>>>(grk, 512, 1536, wrecT, 1536, 512);
    transpose_f32_f16<<<dim3(32, 32), 256, 0, stream>>>(fcw, 1024, 1000, fcT, 1024, 1024);

    bn_stats<<<256, 256, 0, stream>>>(x, gsum, gsumsq);
    bn_apply<<<16000, 256, 0, stream>>>(x, gsum, gsumsq, gamma, beta, xpad);

    // conv0: A[t][kk] = xpad_flat[160 t + kk], K padded 400->448 (zero weights)
    gemm16<0><<<dim3(13, 4, 32), 256, 0, stream>>>(xpad, 160, (long)TXP * CIN, w0T, 448, 0,
        800, 512, 7, b0, nullptr, 0, hbufA, (long)THP * DH, nullptr);

    const f16* tin = hbufA; f16* tout = hbufB;
    for (int i = 0; i < 4; i++) {
        gemm16<1><<<dim3(13, 4, 32), 256, 0, stream>>>(tin, 512, (long)THP * DH,
            tcrT + (size_t)i * 512 * 2560, 2560, 0,
            800, 512, 40, tcrb + i * 512, tin, (long)THP * DH, tout, (long)THP * DH, nullptr);
        const f16* t2 = tout; tout = (f16*)tin; tin = t2;
    }
    const f16* enc = tin;   // = hbufA after 4 swaps

    gru_seq<<<8, 256, 0, stream>>>(wrecT, gk, gbias, ytrue, Hc, cnt);

    // scores[b][u][t] = Hc[u][b][:512] . enc[b][t][:]
    gemm16<2><<<dim3(4, 7, 32), 256, 0, stream>>>(Hc, 32 * 1024, 1024, enc + 2 * DH, 512, (long)THP * DH,
        200, 800, 8, nullptr, nullptr, 0, nullptr, 0, scores);
    row_softmax<<<6400, 256, 0, stream>>>(scores, 800);
    ctx_kernel<<<dim3(32, 13), 256, 0, stream>>>(scores, enc, Hc);

    // logits[b][u][v] = Hc_row(u*32+b)[0:1024] @ fcT + fc_b  -> d_out
    gemm16<3><<<dim3(100, 8, 1), 256, 0, stream>>>(Hc, 1024, 0, fcT, 1024, 0,
        6400, 1000, 16, fcb, nullptr, 0, nullptr, 0, out);
    row_softmax<<<6400, 256, 0, stream>>>(out, 1000);
}

// Round 4
// 2358.735 us; speedup vs baseline: 1.4343x; 1.0017x over previous
//
#include <hip/hip_runtime.h>
#include <cstdint>

typedef _Float16 f16;
typedef __attribute__((ext_vector_type(2))) _Float16 f16x2;
typedef __attribute__((ext_vector_type(8))) _Float16 f16x8;
typedef __attribute__((ext_vector_type(4))) float f32x4;
typedef __attribute__((ext_vector_type(2))) float f32x2;
typedef __attribute__((ext_vector_type(8))) unsigned short us8;   // 16 B — staging vector

#define NB   32
#define TIN  1600
#define CIN  80
#define TOUT 800
#define DH   512
#define NV   1000
#define NU   200
#define TXP  1604   // xpad time rows (1 left pad + 1600 + 3 tail)
#define THP  804    // conv buffer time rows (2 pad each side)
#define EPSB 1e-3f

// write-through (coherent-point) f16 store: no L2 dirty line -> no wbl2 needed
__device__ __forceinline__ void st_sys_f16(f16* p, float v)
{
    f16 h = (f16)v;
    short s; __builtin_memcpy(&s, &h, 2);
    int si = (int)s;
    asm volatile("global_store_short %0, %1, off sc0 sc1"
                 :: "v"(p), "v"(si) : "memory");
}

// ---------------------------------------------------------------- init
__global__ void init_zero(float* gsum, float* gsumsq,
                          unsigned long long* cnt, f16* xpad, f16* hbufA, f16* hbufB)
{
    int tid = blockIdx.x * 256 + threadIdx.x;
    int stride = gridDim.x * 256;
    if (blockIdx.x == 0) {
        if (threadIdx.x < 80) { gsum[threadIdx.x] = 0.f; gsumsq[threadIdx.x] = 0.f; }
        if (threadIdx.x == 255) *cnt = 0ull;
    }
    // xpad zero rows: t'=0, 1601..1603 per b
    for (int i = tid; i < NB * 4 * CIN; i += stride) {
        int b = i / (4 * CIN), rr = (i / CIN) % 4, c = i % CIN;
        int row = (rr == 0) ? 0 : (1600 + rr);
        xpad[((long)b * TXP + row) * CIN + c] = (f16)0.f;
    }
    // hbuf zero rows: t'=0,1,802,803 per b, both buffers
    for (int i = tid; i < 2 * NB * 4 * DH; i += stride) {
        int q = i; int buf = q / (NB * 4 * DH); q %= NB * 4 * DH;
        int b = q / (4 * DH); int rr = (q / DH) % 4; int dd = q % DH;
        int row = (rr < 2) ? rr : (800 + rr);
        f16* hb = buf ? hbufB : hbufA;
        hb[((long)b * THP + row) * DH + dd] = (f16)0.f;
    }
}

// ---------------------------------------------------------------- transpose f32 -> f16 (out[c][r] = in[r][c], OOB -> 0)
__global__ void transpose_f32_f16(const float* __restrict__ in, int R, int C,
                                  f16* __restrict__ out, int outRows, int outCols)
{
    __shared__ float t[32][33];
    int c0 = blockIdx.x * 32, r0 = blockIdx.y * 32;
    int x = threadIdx.x & 31, y = threadIdx.x >> 5;
    for (int i = y; i < 32; i += 8) {
        int r = r0 + i, c = c0 + x;
        t[i][x] = (r < R && c < C) ? in[(long)r * C + c] : 0.0f;
    }
    __syncthreads();
    for (int i = y; i < 32; i += 8) {
        int orow = c0 + i, ocol = r0 + x;
        if (orow < outRows && ocol < outCols)
            out[(long)orow * outCols + ocol] = (f16)t[x][i];
    }
}

// ---------------------------------------------------------------- batchnorm
__global__ void bn_stats(const float* __restrict__ x, float* gsum, float* gsumsq)
{
    __shared__ float ls[240], ls2[240];
    const float* base = x + (long)blockIdx.x * 200 * CIN;
    int tid = threadIdx.x;
    if (tid < 240) {
        int c = tid % 80, rg = tid / 80;
        float s = 0.f, s2 = 0.f;
        for (int r = rg; r < 200; r += 3) {
            float v = base[r * CIN + c];
            s += v; s2 += v * v;
        }
        ls[tid] = s; ls2[tid] = s2;
    }
    __syncthreads();
    if (tid < 80) {
        atomicAdd(&gsum[tid],   ls[tid] + ls[tid + 80] + ls[tid + 160]);
        atomicAdd(&gsumsq[tid], ls2[tid] + ls2[tid + 80] + ls2[tid + 160]);
    }
}

__global__ void bn_apply(const float* __restrict__ x, const float* __restrict__ gsum,
                         const float* __restrict__ gsumsq, const float* __restrict__ gamma,
                         const float* __restrict__ beta, f16* __restrict__ xpad)
{
    long idx = (long)blockIdx.x * 256 + threadIdx.x;
    if (idx >= (long)NB * TIN * CIN) return;
    int c = (int)(idx % CIN);
    long bt = idx / CIN;
    int t = (int)(bt % TIN); int b = (int)(bt / TIN);
    float mean = gsum[c] * (1.f / 51200.f);
    float var  = gsumsq[c] * (1.f / 51200.f) - mean * mean;
    float sc = gamma[c] * rsqrtf(var + EPSB);
    float sh = beta[c] - mean * sc;
    xpad[((long)b * TXP + t + 1) * CIN + c] = (f16)(x[idx] * sc + sh);
}

// ---------------------------------------------------------------- generic fp16 MFMA GEMM (64x128 tile, K in chunks of 64)
// MODE 0: conv0 (relu+bias -> f16 padded buf)   MODE 1: tcr (relu+bias+residual)
// MODE 2: attention scores (f32)                MODE 3: fc (bias -> f32 logits in d_out)
template<int MODE>
__launch_bounds__(256)
__global__ void gemm16(const f16* __restrict__ Ab, long strideA, long slabA,
                       const f16* __restrict__ Bb, long strideB, long slabB,
                       int M, int N, int Kchunks,
                       const float* __restrict__ bias,
                       const f16* __restrict__ resid, long slabR,
                       f16* __restrict__ outH, long slabO,
                       float* __restrict__ outF)
{
    __shared__ f16 As[64][72];
    __shared__ f16 Bs[128][72];
    const int b = blockIdx.z;
    const f16* Abase = Ab + (long)b * slabA;
    const f16* Bbase = Bb + (long)b * slabB;
    const int m0 = blockIdx.x * 64, n0 = blockIdx.y * 128;
    const int tid = threadIdx.x;
    const int lane = tid & 63, wv = tid >> 6;
    const int lm = lane & 15, lk = lane >> 4;

    f32x4 vzero = {0.f, 0.f, 0.f, 0.f};
    f32x4 acc[4][2];
#pragma unroll
    for (int i = 0; i < 4; i++) { acc[i][0] = vzero; acc[i][1] = vzero; }

    const int srow = tid >> 3, scol = (tid & 7) * 8;

    for (int kc = 0; kc < Kchunks; kc++) {
        int kb = kc * 64;
#pragma unroll
        for (int p = 0; p < 2; p++) {
            int r = srow + p * 32;
            int m = m0 + r; if (m > M - 1) m = M - 1;
            *(us8*)&As[r][scol] = *(const us8*)(Abase + (long)m * strideA + kb + scol);
        }
#pragma unroll
        for (int p = 0; p < 4; p++) {
            int r = srow + p * 32;
            int n = n0 + r; if (n > N - 1) n = N - 1;
            *(us8*)&Bs[r][scol] = *(const us8*)(Bbase + (long)n * strideB + kb + scol);
        }
        __syncthreads();
#pragma unroll
        for (int ks = 0; ks < 2; ks++) {
            f16x8 af[4], bf[2];
#pragma unroll
            for (int mt = 0; mt < 4; mt++)
                af[mt] = *(const f16x8*)&As[mt * 16 + lm][ks * 32 + lk * 8];
#pragma unroll
            for (int nt = 0; nt < 2; nt++)
                bf[nt] = *(const f16x8*)&Bs[wv * 32 + nt * 16 + lm][ks * 32 + lk * 8];
#pragma unroll
            for (int mt = 0; mt < 4; mt++)
#pragma unroll
                for (int nt = 0; nt < 2; nt++)
                    acc[mt][nt] = __builtin_amdgcn_mfma_f32_16x16x32_f16(af[mt], bf[nt], acc[mt][nt], 0, 0, 0);
        }
        __syncthreads();
    }
#pragma unroll
    for (int mt = 0; mt < 4; mt++) {
#pragma unroll
        for (int nt = 0; nt < 2; nt++) {
            int n = n0 + wv * 32 + nt * 16 + lm;
#pragma unroll
            for (int reg = 0; reg < 4; reg++) {
                int m = m0 + mt * 16 + lk * 4 + reg;
                if (m >= M || n >= N) continue;
                float v = acc[mt][nt][reg];
                if (MODE == 0) {
                    v += bias[n]; v = v > 0.f ? v : 0.f;
                    outH[(long)b * slabO + (long)(2 + m) * DH + n] = (f16)v;
                } else if (MODE == 1) {
                    v += bias[n]; v = v > 0.f ? v : 0.f;
                    v += (float)resid[(long)b * slabR + (long)(2 + m) * DH + n];
                    outH[(long)b * slabO + (long)(2 + m) * DH + n] = (f16)v;
                } else if (MODE == 2) {
                    outF[((long)b * NU + m) * 800 + n] = v;
                } else {
                    v += bias[n];
                    int u = m >> 5, bb = m & 31;
                    outF[((long)bb * NU + u) * 1000 + n] = v;
                }
            }
        }
    }
}

// ---------------------------------------------------------------- GRU: persistent 8-WG kernel, weights resident in VGPRs.
// h columns owned per-lane in f32 regs; cross-WG exchange via Hc only, using
// write-through (sc0 sc1) stores -> no L2 dirty data -> RELAXED flag add (no
// buffer_wbl2) and no acquire-invalidate on the read side (each Hc line is
// written once and only read after its flag trips, so reader L2s are never stale).
__launch_bounds__(256, 1)
__global__ void gru_seq(const f16* __restrict__ wrecT, const float* __restrict__ gk,
                        const float* __restrict__ gbias, const int* __restrict__ ytrue,
                        f16* __restrict__ Hc, unsigned long long* __restrict__ cnt)
{
    __shared__ int yl[NU * 32];                  // yl[u*32+b]
    const int tid = threadIdx.x;
    const int lane = tid & 63, wv = tid >> 6;
    const int gw = blockIdx.x * 4 + wv;          // gate-triple index 0..31
    const int lm = lane & 15, lk = lane >> 4;
    const int j = gw * 16 + lm;                  // hidden column 0..511

    // stage all teacher-forcing labels once (u = 0..199 of the 201 columns)
    for (int i = tid; i < NU * 32; i += 256) {
        int b = i / NU, u = i - b * NU;
        yl[u * 32 + b] = ytrue[b * 201 + u];
    }

    // resident B-fragments for z/r/c gate columns: wf[g][ks]
    f16x8 wf[3][16];
#pragma unroll
    for (int g = 0; g < 3; g++)
#pragma unroll
        for (int ks = 0; ks < 16; ks++)
            wf[g][ks] = *(const f16x8*)&wrecT[(long)(g * 512 + j) * 512 + ks * 32 + lk * 8];

    const float biz = gbias[j],        bir = gbias[512 + j],        bic = gbias[1024 + j];
    const float brz = gbias[1536 + j], brr = gbias[1536 + 512 + j], brc = gbias[1536 + 1024 + j];
    f32x4 vzero = {0.f, 0.f, 0.f, 0.f};

    __syncthreads();   // yl visible

    // per-lane persistent h (own columns) + double-buffered gk gather
    float hold[8];
    float nxz[8], nxr[8], nxh[8], mxz[8], mxr[8], mxh[8];
#pragma unroll
    for (int s = 0; s < 8; s++) {
        hold[s] = 0.f;
        int b = ((s >> 2) << 4) + lk * 4 + (s & 3);
        const float* gkr = gk + (long)yl[b] * 1536;        // u = 0
        nxz[s] = gkr[j]; nxr[s] = gkr[512 + j]; nxh[s] = gkr[1024 + j];
    }

    for (int u = 0; u < NU; u++) {
        // prefetch gather for u+1 (gk is constant/read-only; overlaps barrier wait)
        int up = (u < NU - 1) ? u + 1 : u;
#pragma unroll
        for (int s = 0; s < 8; s++) {
            int b = ((s >> 2) << 4) + lk * 4 + (s & 3);
            const float* gkr = gk + (long)yl[up * 32 + b] * 1536;
            mxz[s] = gkr[j]; mxr[s] = gkr[512 + j]; mxh[s] = gkr[1024 + j];
        }

        f32x4 acc[3][2];
#pragma unroll
        for (int g = 0; g < 3; g++) { acc[g][0] = vzero; acc[g][1] = vzero; }

        if (u > 0) {
            if (tid == 0) {
                unsigned long long target = 8ull * (unsigned long long)u;
                while (__hip_atomic_load(cnt, __ATOMIC_RELAXED, __HIP_MEMORY_SCOPE_AGENT) < target)
                    __builtin_amdgcn_s_sleep(1);
            }
            __syncthreads();
            // A-fragments directly from Hc[u-1] (fresh lines, L3-sourced)
            const f16* hrow = Hc + (long)(u - 1) * 32 * 1024 + lk * 8;
#pragma unroll
            for (int ks = 0; ks < 16; ks++) {
                f16x8 a0 = *(const f16x8*)(hrow + (long)lm * 1024 + ks * 32);
                f16x8 a1 = *(const f16x8*)(hrow + (long)(16 + lm) * 1024 + ks * 32);
#pragma unroll
                for (int g = 0; g < 3; g++) {
                    acc[g][0] = __builtin_amdgcn_mfma_f32_16x16x32_f16(a0, wf[g][ks], acc[g][0], 0, 0, 0);
                    acc[g][1] = __builtin_amdgcn_mfma_f32_16x16x32_f16(a1, wf[g][ks], acc[g][1], 0, 0, 0);
                }
            }
        }

        // gates + state update (fp32, h kept in regs)
#pragma unroll
        for (int mt = 0; mt < 2; mt++) {
#pragma unroll
            for (int reg = 0; reg < 4; reg++) {
                int s = mt * 4 + reg;
                int b = mt * 16 + lk * 4 + reg;
                float hz = acc[0][mt][reg] + brz;
                float hr = acc[1][mt][reg] + brr;
                float hh = acc[2][mt][reg] + brc;
                float z = 1.f / (1.f + __expf(-(nxz[s] + biz + hz)));
                float r = 1.f / (1.f + __expf(-(nxr[s] + bir + hr)));
                float cd = tanhf(nxh[s] + bic + r * hh);
                float hnew = z * hold[s] + (1.f - z) * cd;
                hold[s] = hnew;
                st_sys_f16(&Hc[((long)u * 32 + b) * 1024 + j], hnew);
            }
        }
#pragma unroll
        for (int s = 0; s < 8; s++) { nxz[s] = mxz[s]; nxr[s] = mxr[s]; nxh[s] = mxh[s]; }

        if (u < NU - 1) {
            asm volatile("s_waitcnt vmcnt(0)" ::: "memory");  // drain asm write-through stores
            __syncthreads();                                  // all waves drained
            if (tid == 0)
                __hip_atomic_fetch_add(cnt, 1ull, __ATOMIC_RELAXED, __HIP_MEMORY_SCOPE_AGENT);
        }
    }
}

// ---------------------------------------------------------------- row softmax in place (len <= 1024)
__global__ void row_softmax(float* __restrict__ base, int len)
{
    float* s = base + (long)blockIdx.x * len;
    int tid = threadIdx.x;
    float v[4]; float mx = -1e30f;
#pragma unroll
    for (int i = 0; i < 4; i++) {
        int idx = tid + i * 256;
        v[i] = (idx < len) ? s[idx] : -1e30f;
        mx = fmaxf(mx, v[i]);
    }
#pragma unroll
    for (int off = 32; off; off >>= 1) mx = fmaxf(mx, __shfl_xor(mx, off));
    __shared__ float red[4], red2[4];
    if ((tid & 63) == 0) red[tid >> 6] = mx;
    __syncthreads();
    mx = fmaxf(fmaxf(red[0], red[1]), fmaxf(red[2], red[3]));
    float sum = 0.f;
#pragma unroll
    for (int i = 0; i < 4; i++) { v[i] = __expf(v[i] - mx); sum += v[i]; }
#pragma unroll
    for (int off = 32; off; off >>= 1) sum += __shfl_xor(sum, off);
    if ((tid & 63) == 0) red2[tid >> 6] = sum;
    __syncthreads();
    sum = red2[0] + red2[1] + red2[2] + red2[3];
    float inv = 1.f / sum;
#pragma unroll
    for (int i = 0; i < 4; i++) {
        int idx = tid + i * 256;
        if (idx < len) s[idx] = v[i] * inv;
    }
}

// ---------------------------------------------------------------- ctx: ctx[b][u][:] = alpha[b][u][:] @ enc[b], u-blocked by 16
__global__ void ctx_kernel(const float* __restrict__ alpha, const f16* __restrict__ enc,
                           f16* __restrict__ Hc)
{
    __shared__ float al[800][18];
    int b = blockIdx.x, ut = blockIdx.y;
    int u0 = ut * 16;
    int tid = threadIdx.x;
    for (int ul = 0; ul < 16; ul++) {
        int u = u0 + ul;
        if (u < NU) {
            const float* arow = alpha + ((long)b * NU + u) * 800;
            for (int t = tid; t < 800; t += 256) al[t][ul] = arow[t];
        } else {
            for (int t = tid; t < 800; t += 256) al[t][ul] = 0.f;
        }
    }
    __syncthreads();
    int d0 = tid * 2;
    float a0[16], a1[16];
#pragma unroll
    for (int i = 0; i < 16; i++) { a0[i] = 0.f; a1[i] = 0.f; }
    const f16* encb = enc + ((long)b * THP + 2) * DH + d0;
    for (int t = 0; t < 800; t++) {
        f16x2 e = *(const f16x2*)&encb[(long)t * DH];
        float f0 = (float)e.x, f1 = (float)e.y;
#pragma unroll
        for (int g = 0; g < 8; g++) {
            f32x2 ap = *(const f32x2*)&al[t][2 * g];
            a0[2 * g]     += ap.x * f0; a0[2 * g + 1] += ap.y * f0;
            a1[2 * g]     += ap.x * f1; a1[2 * g + 1] += ap.y * f1;
        }
    }
#pragma unroll
    for (int ul = 0; ul < 16; ul++) {
        int u = u0 + ul;
        if (u < NU) {
            Hc[((long)u * 32 + b) * 1024 + 512 + d0]     = (f16)a0[ul];
            Hc[((long)u * 32 + b) * 1024 + 512 + d0 + 1] = (f16)a1[ul];
        }
    }
}

// ---------------------------------------------------------------- launcher
extern "C" void kernel_launch(void* const* d_in, const int* in_sizes, int n_in,
                              void* d_out, int out_size, void* d_ws, size_t ws_size,
                              hipStream_t stream)
{
    const float* x     = (const float*)d_in[0];
    const int*   ytrue = (const int*)d_in[1];
    const float* gamma = (const float*)d_in[2];
    const float* beta  = (const float*)d_in[3];
    const float* w0    = (const float*)d_in[4];
    const float* b0    = (const float*)d_in[5];
    const float* tcrw  = (const float*)d_in[6];
    const float* tcrb  = (const float*)d_in[7];
    const float* gk    = (const float*)d_in[8];
    const float* grk   = (const float*)d_in[9];
    const float* gbias = (const float*)d_in[10];
    const float* fcw   = (const float*)d_in[11];
    const float* fcb   = (const float*)d_in[12];
    float* out = (float*)d_out;
    (void)in_sizes; (void)n_in; (void)out_size; (void)ws_size;

    char* ws = (char*)d_ws;
    size_t o = 0;
    auto alloc = [&](size_t bytes) { size_t r = o; o += (bytes + 255) & ~(size_t)255; return r; };
    f16*   xpad   = (f16*)(ws + alloc((size_t)NB * TXP * CIN * 2));
    f16*   hbufA  = (f16*)(ws + alloc((size_t)NB * THP * DH * 2));
    f16*   hbufB  = (f16*)(ws + alloc((size_t)NB * THP * DH * 2));
    f16*   Hc     = (f16*)(ws + alloc((size_t)NU * NB * 1024 * 2));
    float* scores = (float*)(ws + alloc((size_t)NB * NU * 800 * 4));
    f16*   w0T    = (f16*)(ws + alloc((size_t)512 * 448 * 2));
    f16*   tcrT   = (f16*)(ws + alloc((size_t)4 * 512 * 2560 * 2));
    f16*   wrecT  = (f16*)(ws + alloc((size_t)1536 * 512 * 2));
    f16*   fcT    = (f16*)(ws + alloc((size_t)1024 * 1024 * 2));
    float* gsum   = (float*)(ws + alloc(80 * 4));
    float* gsumsq = (float*)(ws + alloc(80 * 4));
    unsigned long long* cnt = (unsigned long long*)(ws + alloc(64));

    init_zero<<<64, 256, 0, stream>>>(gsum, gsumsq, cnt, xpad, hbufA, hbufB);
    transpose_f32_f16<<<dim3(16, 14), 256, 0, stream>>>(w0, 400, 512, w0T, 512, 448);
    for (int i = 0; i < 4; i++)
        transpose_f32_f16<<<dim3(16, 80), 256, 0, stream>>>(tcrw + (size_t)i * 2560 * 512, 2560, 512,
                                                            tcrT + (size_t)i * 512 * 2560, 512, 2560);
    transpose_f32_f16<<<dim3(48, 16), 256, 0, stream>>>(grk, 512, 1536, wrecT, 1536, 512);
    transpose_f32_f16<<<dim3(32, 32), 256, 0, stream>>>(fcw, 1024, 1000, fcT, 1024, 1024);

    bn_stats<<<256, 256, 0, stream>>>(x, gsum, gsumsq);
    bn_apply<<<16000, 256, 0, stream>>>(x, gsum, gsumsq, gamma, beta, xpad);

    // conv0: A[t][kk] = xpad_flat[160 t + kk], K padded 400->448 (zero weights)
    gemm16<0><<<dim3(13, 4, 32), 256, 0, stream>>>(xpad, 160, (long)TXP * CIN, w0T, 448, 0,
        800, 512, 7, b0, nullptr, 0, hbufA, (long)THP * DH, nullptr);

    const f16* tin = hbufA; f16* tout = hbufB;
    for (int i = 0; i < 4; i++) {
        gemm16<1><<<dim3(13, 4, 32), 256, 0, stream>>>(tin, 512, (long)THP * DH,
            tcrT + (size_t)i * 512 * 2560, 2560, 0,
            800, 512, 40, tcrb + i * 512, tin, (long)THP * DH, tout, (long)THP * DH, nullptr);
        const f16* t2 = tout; tout = (f16*)tin; tin = t2;
    }
    const f16* enc = tin;   // = hbufA after 4 swaps

    gru_seq<<<8, 256, 0, stream>>>(wrecT, gk, gbias, ytrue, Hc, cnt);

    // scores[b][u][t] = Hc[u][b][:512] . enc[b][t][:]
    gemm16<2><<<dim3(4, 7, 32), 256, 0, stream>>>(Hc, 32 * 1024, 1024, enc + 2 * DH, 512, (long)THP * DH,
        200, 800, 8, nullptr, nullptr, 0, nullptr, 0, scores);
    row_softmax<<<6400, 256, 0, stream>>>(scores, 800);
    ctx_kernel<<<dim3(32, 13), 256, 0, stream>>>(scores, enc, Hc);

    // logits[b][u][v] = Hc_row(u*32+b)[0:1024] @ fcT + fc_b  -> d_out
    gemm16<3><<<dim3(100, 8, 1), 256, 0, stream>>>(Hc, 1024, 0, fcT, 1024, 0,
        6400, 1000, 16, fcb, nullptr, 0, nullptr, 0, out);
    row_softmax<<<6400, 256, 0, stream>>>(out, 1000);
}

// Round 5
// 2345.612 us; speedup vs baseline: 1.4424x; 1.0056x over previous
//
#include <hip/hip_runtime.h>
#include <cstdint>

typedef _Float16 f16;
typedef __attribute__((ext_vector_type(2))) _Float16 f16x2;
typedef __attribute__((ext_vector_type(8))) _Float16 f16x8;
typedef __attribute__((ext_vector_type(4))) float f32x4;
typedef __attribute__((ext_vector_type(2))) float f32x2;
typedef __attribute__((ext_vector_type(8))) unsigned short us8;   // 16 B — staging vector
typedef __attribute__((ext_vector_type(4))) int i32x4;

#define NB   32
#define TIN  1600
#define CIN  80
#define TOUT 800
#define DH   512
#define NV   1000
#define NU   200
#define TXP  1604   // xpad time rows (1 left pad + 1600 + 3 tail)
#define THP  804    // conv buffer time rows (2 pad each side)
#define EPSB 1e-3f

// write-through (coherence-point) stores: no L2 dirty line, visible at L3
__device__ __forceinline__ void st_sys_f16(f16* p, float v)
{
    f16 h = (f16)v;
    short s; __builtin_memcpy(&s, &h, 2);
    int si = (int)s;
    asm volatile("global_store_short %0, %1, off sc0 sc1"
                 :: "v"(p), "v"(si) : "memory");
}
__device__ __forceinline__ void st_sys_i32(int* p, int v)
{
    asm volatile("global_store_dword %0, %1, off sc0 sc1"
                 :: "v"(p), "v"(v) : "memory");
}

// poll 8 contiguous flag words (one L3-coherent load pair) until all == target
__device__ __forceinline__ void poll8(const int* fl, int target)
{
    i32x4 a, b;
    while (true) {
        asm volatile("global_load_dwordx4 %0, %2, off sc1\n\t"
                     "global_load_dwordx4 %1, %3, off sc1\n\t"
                     "s_waitcnt vmcnt(0)"
                     : "=&v"(a), "=&v"(b)
                     : "v"(fl), "v"(fl + 4)
                     : "memory");
        if (a.x == target && a.y == target && a.z == target && a.w == target &&
            b.x == target && b.y == target && b.z == target && b.w == target) break;
        __builtin_amdgcn_s_sleep(1);
    }
}

__device__ __forceinline__ float fast_tanh(float x)
{
    // 1 - 2/(exp(2x)+1); saturates correctly for |x| large
    return 1.f - 2.f / (__expf(2.f * x) + 1.f);
}

// ---------------------------------------------------------------- init
__global__ void init_zero(float* gsum, float* gsumsq,
                          int* flags, f16* xpad, f16* hbufA, f16* hbufB)
{
    int tid = blockIdx.x * 256 + threadIdx.x;
    int stride = gridDim.x * 256;
    if (blockIdx.x == 0) {
        if (threadIdx.x < 80) { gsum[threadIdx.x] = 0.f; gsumsq[threadIdx.x] = 0.f; }
    }
    for (int i = tid; i < NU * 8; i += stride) flags[i] = 0;
    // xpad zero rows: t'=0, 1601..1603 per b
    for (int i = tid; i < NB * 4 * CIN; i += stride) {
        int b = i / (4 * CIN), rr = (i / CIN) % 4, c = i % CIN;
        int row = (rr == 0) ? 0 : (1600 + rr);
        xpad[((long)b * TXP + row) * CIN + c] = (f16)0.f;
    }
    // hbuf zero rows: t'=0,1,802,803 per b, both buffers
    for (int i = tid; i < 2 * NB * 4 * DH; i += stride) {
        int q = i; int buf = q / (NB * 4 * DH); q %= NB * 4 * DH;
        int b = q / (4 * DH); int rr = (q / DH) % 4; int dd = q % DH;
        int row = (rr < 2) ? rr : (800 + rr);
        f16* hb = buf ? hbufB : hbufA;
        hb[((long)b * THP + row) * DH + dd] = (f16)0.f;
    }
}

// ---------------------------------------------------------------- transpose f32 -> f16 (out[c][r] = in[r][c], OOB -> 0)
__global__ void transpose_f32_f16(const float* __restrict__ in, int R, int C,
                                  f16* __restrict__ out, int outRows, int outCols)
{
    __shared__ float t[32][33];
    int c0 = blockIdx.x * 32, r0 = blockIdx.y * 32;
    int x = threadIdx.x & 31, y = threadIdx.x >> 5;
    for (int i = y; i < 32; i += 8) {
        int r = r0 + i, c = c0 + x;
        t[i][x] = (r < R && c < C) ? in[(long)r * C + c] : 0.0f;
    }
    __syncthreads();
    for (int i = y; i < 32; i += 8) {
        int orow = c0 + i, ocol = r0 + x;
        if (orow < outRows && ocol < outCols)
            out[(long)orow * outCols + ocol] = (f16)t[x][i];
    }
}

// ---------------------------------------------------------------- batchnorm
__global__ void bn_stats(const float* __restrict__ x, float* gsum, float* gsumsq)
{
    __shared__ float ls[240], ls2[240];
    const float* base = x + (long)blockIdx.x * 200 * CIN;
    int tid = threadIdx.x;
    if (tid < 240) {
        int c = tid % 80, rg = tid / 80;
        float s = 0.f, s2 = 0.f;
        for (int r = rg; r < 200; r += 3) {
            float v = base[r * CIN + c];
            s += v; s2 += v * v;
        }
        ls[tid] = s; ls2[tid] = s2;
    }
    __syncthreads();
    if (tid < 80) {
        atomicAdd(&gsum[tid],   ls[tid] + ls[tid + 80] + ls[tid + 160]);
        atomicAdd(&gsumsq[tid], ls2[tid] + ls2[tid + 80] + ls2[tid + 160]);
    }
}

__global__ void bn_apply(const float* __restrict__ x, const float* __restrict__ gsum,
                         const float* __restrict__ gsumsq, const float* __restrict__ gamma,
                         const float* __restrict__ beta, f16* __restrict__ xpad)
{
    long idx = (long)blockIdx.x * 256 + threadIdx.x;
    if (idx >= (long)NB * TIN * CIN) return;
    int c = (int)(idx % CIN);
    long bt = idx / CIN;
    int t = (int)(bt % TIN); int b = (int)(bt / TIN);
    float mean = gsum[c] * (1.f / 51200.f);
    float var  = gsumsq[c] * (1.f / 51200.f) - mean * mean;
    float sc = gamma[c] * rsqrtf(var + EPSB);
    float sh = beta[c] - mean * sc;
    xpad[((long)b * TXP + t + 1) * CIN + c] = (f16)(x[idx] * sc + sh);
}

// ---------------------------------------------------------------- generic fp16 MFMA GEMM (64x128 tile, K in chunks of 64)
// MODE 0: conv0 (relu+bias -> f16 padded buf)   MODE 1: tcr (relu+bias+residual)
// MODE 2: attention scores (f32)                MODE 3: fc (bias -> f32 logits in d_out)
template<int MODE>
__launch_bounds__(256)
__global__ void gemm16(const f16* __restrict__ Ab, long strideA, long slabA,
                       const f16* __restrict__ Bb, long strideB, long slabB,
                       int M, int N, int Kchunks,
                       const float* __restrict__ bias,
                       const f16* __restrict__ resid, long slabR,
                       f16* __restrict__ outH, long slabO,
                       float* __restrict__ outF)
{
    __shared__ f16 As[64][72];
    __shared__ f16 Bs[128][72];
    const int b = blockIdx.z;
    const f16* Abase = Ab + (long)b * slabA;
    const f16* Bbase = Bb + (long)b * slabB;
    const int m0 = blockIdx.x * 64, n0 = blockIdx.y * 128;
    const int tid = threadIdx.x;
    const int lane = tid & 63, wv = tid >> 6;
    const int lm = lane & 15, lk = lane >> 4;

    f32x4 vzero = {0.f, 0.f, 0.f, 0.f};
    f32x4 acc[4][2];
#pragma unroll
    for (int i = 0; i < 4; i++) { acc[i][0] = vzero; acc[i][1] = vzero; }

    const int srow = tid >> 3, scol = (tid & 7) * 8;

    for (int kc = 0; kc < Kchunks; kc++) {
        int kb = kc * 64;
#pragma unroll
        for (int p = 0; p < 2; p++) {
            int r = srow + p * 32;
            int m = m0 + r; if (m > M - 1) m = M - 1;
            *(us8*)&As[r][scol] = *(const us8*)(Abase + (long)m * strideA + kb + scol);
        }
#pragma unroll
        for (int p = 0; p < 4; p++) {
            int r = srow + p * 32;
            int n = n0 + r; if (n > N - 1) n = N - 1;
            *(us8*)&Bs[r][scol] = *(const us8*)(Bbase + (long)n * strideB + kb + scol);
        }
        __syncthreads();
#pragma unroll
        for (int ks = 0; ks < 2; ks++) {
            f16x8 af[4], bf[2];
#pragma unroll
            for (int mt = 0; mt < 4; mt++)
                af[mt] = *(const f16x8*)&As[mt * 16 + lm][ks * 32 + lk * 8];
#pragma unroll
            for (int nt = 0; nt < 2; nt++)
                bf[nt] = *(const f16x8*)&Bs[wv * 32 + nt * 16 + lm][ks * 32 + lk * 8];
#pragma unroll
            for (int mt = 0; mt < 4; mt++)
#pragma unroll
                for (int nt = 0; nt < 2; nt++)
                    acc[mt][nt] = __builtin_amdgcn_mfma_f32_16x16x32_f16(af[mt], bf[nt], acc[mt][nt], 0, 0, 0);
        }
        __syncthreads();
    }
#pragma unroll
    for (int mt = 0; mt < 4; mt++) {
#pragma unroll
        for (int nt = 0; nt < 2; nt++) {
            int n = n0 + wv * 32 + nt * 16 + lm;
#pragma unroll
            for (int reg = 0; reg < 4; reg++) {
                int m = m0 + mt * 16 + lk * 4 + reg;
                if (m >= M || n >= N) continue;
                float v = acc[mt][nt][reg];
                if (MODE == 0) {
                    v += bias[n]; v = v > 0.f ? v : 0.f;
                    outH[(long)b * slabO + (long)(2 + m) * DH + n] = (f16)v;
                } else if (MODE == 1) {
                    v += bias[n]; v = v > 0.f ? v : 0.f;
                    v += (float)resid[(long)b * slabR + (long)(2 + m) * DH + n];
                    outH[(long)b * slabO + (long)(2 + m) * DH + n] = (f16)v;
                } else if (MODE == 2) {
                    outF[((long)b * NU + m) * 800 + n] = v;
                } else {
                    v += bias[n];
                    int u = m >> 5, bb = m & 31;
                    outF[((long)bb * NU + u) * 1000 + n] = v;
                }
            }
        }
    }
}

// ---------------------------------------------------------------- GRU: persistent 8-WG kernel, weights resident in VGPRs.
// Sync protocol (per step): write-through data stores -> vmcnt(0) -> barrier ->
// tid0 write-through flag store flags[u][wg]=u+1 (no RMW, monotonic addresses).
// Readers: EVERY wave polls the 8-flag line with sc1 loads and proceeds
// independently (no reader barrier, no wake funnel).
__launch_bounds__(256, 1)
__global__ void gru_seq(const f16* __restrict__ wrecT, const float* __restrict__ gk,
                        const float* __restrict__ gbias, const int* __restrict__ ytrue,
                        f16* __restrict__ Hc, int* __restrict__ flags)
{
    __shared__ int yl[NU * 32];                  // yl[u*32+b]
    const int tid = threadIdx.x;
    const int lane = tid & 63, wv = tid >> 6;
    const int gw = blockIdx.x * 4 + wv;          // gate-triple index 0..31
    const int lm = lane & 15, lk = lane >> 4;
    const int j = gw * 16 + lm;                  // hidden column 0..511

    // stage all teacher-forcing labels once (u = 0..199 of the 201 columns)
    for (int i = tid; i < NU * 32; i += 256) {
        int b = i / NU, u = i - b * NU;
        yl[u * 32 + b] = ytrue[b * 201 + u];
    }

    // resident B-fragments for z/r/c gate columns: wf[g][ks]
    f16x8 wf[3][16];
#pragma unroll
    for (int g = 0; g < 3; g++)
#pragma unroll
        for (int ks = 0; ks < 16; ks++)
            wf[g][ks] = *(const f16x8*)&wrecT[(long)(g * 512 + j) * 512 + ks * 32 + lk * 8];

    const float biz = gbias[j],        bir = gbias[512 + j],        bic = gbias[1024 + j];
    const float brz = gbias[1536 + j], brr = gbias[1536 + 512 + j], brc = gbias[1536 + 1024 + j];
    f32x4 vzero = {0.f, 0.f, 0.f, 0.f};

    __syncthreads();   // yl visible

    // per-lane persistent h (own columns) + double-buffered gk gather
    float hold[8];
    float nxz[8], nxr[8], nxh[8], mxz[8], mxr[8], mxh[8];
#pragma unroll
    for (int s = 0; s < 8; s++) {
        hold[s] = 0.f;
        int b = ((s >> 2) << 4) + lk * 4 + (s & 3);
        const float* gkr = gk + (long)yl[b] * 1536;        // u = 0
        nxz[s] = gkr[j]; nxr[s] = gkr[512 + j]; nxh[s] = gkr[1024 + j];
    }

    for (int u = 0; u < NU; u++) {
        // prefetch gather for u+1 (gk constant/read-only; overlaps the flag wait)
        int up = (u < NU - 1) ? u + 1 : u;
#pragma unroll
        for (int s = 0; s < 8; s++) {
            int b = ((s >> 2) << 4) + lk * 4 + (s & 3);
            const float* gkr = gk + (long)yl[up * 32 + b] * 1536;
            mxz[s] = gkr[j]; mxr[s] = gkr[512 + j]; mxh[s] = gkr[1024 + j];
        }

        f32x4 acc[3][2];
#pragma unroll
        for (int g = 0; g < 3; g++) { acc[g][0] = vzero; acc[g][1] = vzero; }

        if (u > 0) {
            poll8(flags + (u - 1) * 8, u);       // every wave, independently
            // A-fragments directly from Hc[u-1] (lines fresh at L3, L2 never stale)
            const f16* hrow = Hc + (long)(u - 1) * 32 * 1024 + lk * 8;
#pragma unroll
            for (int ks = 0; ks < 16; ks++) {
                f16x8 a0 = *(const f16x8*)(hrow + (long)lm * 1024 + ks * 32);
                f16x8 a1 = *(const f16x8*)(hrow + (long)(16 + lm) * 1024 + ks * 32);
#pragma unroll
                for (int g = 0; g < 3; g++) {
                    acc[g][0] = __builtin_amdgcn_mfma_f32_16x16x32_f16(a0, wf[g][ks], acc[g][0], 0, 0, 0);
                    acc[g][1] = __builtin_amdgcn_mfma_f32_16x16x32_f16(a1, wf[g][ks], acc[g][1], 0, 0, 0);
                }
            }
        }

        // gates + state update (fp32, h kept in regs)
#pragma unroll
        for (int mt = 0; mt < 2; mt++) {
#pragma unroll
            for (int reg = 0; reg < 4; reg++) {
                int s = mt * 4 + reg;
                int b = mt * 16 + lk * 4 + reg;
                float hz = acc[0][mt][reg] + brz;
                float hr = acc[1][mt][reg] + brr;
                float hh = acc[2][mt][reg] + brc;
                float z = 1.f / (1.f + __expf(-(nxz[s] + biz + hz)));
                float r = 1.f / (1.f + __expf(-(nxr[s] + bir + hr)));
                float cd = fast_tanh(nxh[s] + bic + r * hh);
                float hnew = z * hold[s] + (1.f - z) * cd;
                hold[s] = hnew;
                st_sys_f16(&Hc[((long)u * 32 + b) * 1024 + j], hnew);
            }
        }
#pragma unroll
        for (int s = 0; s < 8; s++) { nxz[s] = mxz[s]; nxr[s] = mxr[s]; nxh[s] = mxh[s]; }

        if (u < NU - 1) {
            asm volatile("s_waitcnt vmcnt(0)" ::: "memory");  // this wave's stores at L3
            __syncthreads();                                  // => all waves' stores at L3
            if (tid == 0) st_sys_i32(&flags[u * 8 + (int)blockIdx.x], u + 1);
        }
    }
}

// ---------------------------------------------------------------- row softmax in place (len <= 1024)
__global__ void row_softmax(float* __restrict__ base, int len)
{
    float* s = base + (long)blockIdx.x * len;
    int tid = threadIdx.x;
    float v[4]; float mx = -1e30f;
#pragma unroll
    for (int i = 0; i < 4; i++) {
        int idx = tid + i * 256;
        v[i] = (idx < len) ? s[idx] : -1e30f;
        mx = fmaxf(mx, v[i]);
    }
#pragma unroll
    for (int off = 32; off; off >>= 1) mx = fmaxf(mx, __shfl_xor(mx, off));
    __shared__ float red[4], red2[4];
    if ((tid & 63) == 0) red[tid >> 6] = mx;
    __syncthreads();
    mx = fmaxf(fmaxf(red[0], red[1]), fmaxf(red[2], red[3]));
    float sum = 0.f;
#pragma unroll
    for (int i = 0; i < 4; i++) { v[i] = __expf(v[i] - mx); sum += v[i]; }
#pragma unroll
    for (int off = 32; off; off >>= 1) sum += __shfl_xor(sum, off);
    if ((tid & 63) == 0) red2[tid >> 6] = sum;
    __syncthreads();
    sum = red2[0] + red2[1] + red2[2] + red2[3];
    float inv = 1.f / sum;
#pragma unroll
    for (int i = 0; i < 4; i++) {
        int idx = tid + i * 256;
        if (idx < len) s[idx] = v[i] * inv;
    }
}

// ---------------------------------------------------------------- ctx: ctx[b][u][:] = alpha[b][u][:] @ enc[b], u-blocked by 16
__global__ void ctx_kernel(const float* __restrict__ alpha, const f16* __restrict__ enc,
                           f16* __restrict__ Hc)
{
    __shared__ float al[800][18];
    int b = blockIdx.x, ut = blockIdx.y;
    int u0 = ut * 16;
    int tid = threadIdx.x;
    for (int ul = 0; ul < 16; ul++) {
        int u = u0 + ul;
        if (u < NU) {
            const float* arow = alpha + ((long)b * NU + u) * 800;
            for (int t = tid; t < 800; t += 256) al[t][ul] = arow[t];
        } else {
            for (int t = tid; t < 800; t += 256) al[t][ul] = 0.f;
        }
    }
    __syncthreads();
    int d0 = tid * 2;
    float a0[16], a1[16];
#pragma unroll
    for (int i = 0; i < 16; i++) { a0[i] = 0.f; a1[i] = 0.f; }
    const f16* encb = enc + ((long)b * THP + 2) * DH + d0;
    for (int t = 0; t < 800; t++) {
        f16x2 e = *(const f16x2*)&encb[(long)t * DH];
        float f0 = (float)e.x, f1 = (float)e.y;
#pragma unroll
        for (int g = 0; g < 8; g++) {
            f32x2 ap = *(const f32x2*)&al[t][2 * g];
            a0[2 * g]     += ap.x * f0; a0[2 * g + 1] += ap.y * f0;
            a1[2 * g]     += ap.x * f1; a1[2 * g + 1] += ap.y * f1;
        }
    }
#pragma unroll
    for (int ul = 0; ul < 16; ul++) {
        int u = u0 + ul;
        if (u < NU) {
            Hc[((long)u * 32 + b) * 1024 + 512 + d0]     = (f16)a0[ul];
            Hc[((long)u * 32 + b) * 1024 + 512 + d0 + 1] = (f16)a1[ul];
        }
    }
}

// ---------------------------------------------------------------- launcher
extern "C" void kernel_launch(void* const* d_in, const int* in_sizes, int n_in,
                              void* d_out, int out_size, void* d_ws, size_t ws_size,
                              hipStream_t stream)
{
    const float* x     = (const float*)d_in[0];
    const int*   ytrue = (const int*)d_in[1];
    const float* gamma = (const float*)d_in[2];
    const float* beta  = (const float*)d_in[3];
    const float* w0    = (const float*)d_in[4];
    const float* b0    = (const float*)d_in[5];
    const float* tcrw  = (const float*)d_in[6];
    const float* tcrb  = (const float*)d_in[7];
    const float* gk    = (const float*)d_in[8];
    const float* grk   = (const float*)d_in[9];
    const float* gbias = (const float*)d_in[10];
    const float* fcw   = (const float*)d_in[11];
    const float* fcb   = (const float*)d_in[12];
    float* out = (float*)d_out;
    (void)in_sizes; (void)n_in; (void)out_size; (void)ws_size;

    char* ws = (char*)d_ws;
    size_t o = 0;
    auto alloc = [&](size_t bytes) { size_t r = o; o += (bytes + 255) & ~(size_t)255; return r; };
    f16*   xpad   = (f16*)(ws + alloc((size_t)NB * TXP * CIN * 2));
    f16*   hbufA  = (f16*)(ws + alloc((size_t)NB * THP * DH * 2));
    f16*   hbufB  = (f16*)(ws + alloc((size_t)NB * THP * DH * 2));
    f16*   Hc     = (f16*)(ws + alloc((size_t)NU * NB * 1024 * 2));
    float* scores = (float*)(ws + alloc((size_t)NB * NU * 800 * 4));
    f16*   w0T    = (f16*)(ws + alloc((size_t)512 * 448 * 2));
    f16*   tcrT   = (f16*)(ws + alloc((size_t)4 * 512 * 2560 * 2));
    f16*   wrecT  = (f16*)(ws + alloc((size_t)1536 * 512 * 2));
    f16*   fcT    = (f16*)(ws + alloc((size_t)1024 * 1024 * 2));
    float* gsum   = (float*)(ws + alloc(80 * 4));
    float* gsumsq = (float*)(ws + alloc(80 * 4));
    int*   flags  = (int*)(ws + alloc(NU * 8 * 4));

    init_zero<<<64, 256, 0, stream>>>(gsum, gsumsq, flags, xpad, hbufA, hbufB);
    transpose_f32_f16<<<dim3(16, 14), 256, 0, stream>>>(w0, 400, 512, w0T, 512, 448);
    for (int i = 0; i < 4; i++)
        transpose_f32_f16<<<dim3(16, 80), 256, 0, stream>>>(tcrw + (size_t)i * 2560 * 512, 2560, 512,
                                                            tcrT + (size_t)i * 512 * 2560, 512, 2560);
    transpose_f32_f16<<<dim3(48, 16), 256, 0, stream>>>(grk, 512, 1536, wrecT, 1536, 512);
    transpose_f32_f16<<<dim3(32, 32), 256, 0, stream>>>(fcw, 1024, 1000, fcT, 1024, 1024);

    bn_stats<<<256, 256, 0, stream>>>(x, gsum, gsumsq);
    bn_apply<<<16000, 256, 0, stream>>>(x, gsum, gsumsq, gamma, beta, xpad);

    // conv0: A[t][kk] = xpad_flat[160 t + kk], K padded 400->448 (zero weights)
    gemm16<0><<<dim3(13, 4, 32), 256, 0, stream>>>(xpad, 160, (long)TXP * CIN, w0T, 448, 0,
        800, 512, 7, b0, nullptr, 0, hbufA, (long)THP * DH, nullptr);

    const f16* tin = hbufA; f16* tout = hbufB;
    for (int i = 0; i < 4; i++) {
        gemm16<1><<<dim3(13, 4, 32), 256, 0, stream>>>(tin, 512, (long)THP * DH,
            tcrT + (size_t)i * 512 * 2560, 2560, 0,
            800, 512, 40, tcrb + i * 512, tin, (long)THP * DH, tout, (long)THP * DH, nullptr);
        const f16* t2 = tout; tout = (f16*)tin; tin = t2;
    }
    const f16* enc = tin;   // = hbufA after 4 swaps

    gru_seq<<<8, 256, 0, stream>>>(wrecT, gk, gbias, ytrue, Hc, flags);

    // scores[b][u][t] = Hc[u][b][:512] . enc[b][t][:]
    gemm16<2><<<dim3(4, 7, 32), 256, 0, stream>>>(Hc, 32 * 1024, 1024, enc + 2 * DH, 512, (long)THP * DH,
        200, 800, 8, nullptr, nullptr, 0, nullptr, 0, scores);
    row_softmax<<<6400, 256, 0, stream>>>(scores, 800);
    ctx_kernel<<<dim3(32, 13), 256, 0, stream>>>(scores, enc, Hc);

    // logits[b][u][v] = Hc_row(u*32+b)[0:1024] @ fcT + fc_b  -> d_out
    gemm16<3><<<dim3(100, 8, 1), 256, 0, stream>>>(Hc, 1024, 0, fcT, 1024, 0,
        6400, 1000, 16, fcb, nullptr, 0, nullptr, 0, out);
    row_softmax<<<6400, 256, 0, stream>>>(out, 1000);
}